// Round 1
// baseline (2545.345 us; speedup 1.0000x reference)
//
#include <hip/hip_runtime.h>
#include <hip/hip_bf16.h>

#define MA 64
#define F 128
#define NF 16
#define HID 512

// Output layout: [z (N*MA floats), r (N*MA*3 floats), h_new (N*MA*F floats)]
__global__ void pass_kernel(const int* __restrict__ z, const float* __restrict__ r,
                            float* __restrict__ out, int nz, int nr) {
    int i = blockIdx.x * blockDim.x + threadIdx.x;
    if (i < nz) out[i] = (float)z[i];
    else if (i < nz + nr) out[i] = r[i - nz];
}

// One block per molecule. 512 threads.
// LDS: h (bf16 16KB) + w_f (bf16 8KB) + smem (fp32 32KB, u_f | t1-tile) + r/mask (~1.3KB) = ~58KB
__launch_bounds__(512, 1)
__global__ void node_conv_kernel(const int* __restrict__ z, const float* __restrict__ rr,
        const float* __restrict__ h, const float* __restrict__ dist,
        const float* __restrict__ wid, const float* __restrict__ W1,
        const float* __restrict__ b1, const float* __restrict__ W2,
        const float* __restrict__ b2, float* __restrict__ out_h)
{
    const int n = blockIdx.x;
    const int tid = threadIdx.x;

    __shared__ __hip_bfloat16 h_lds[MA * F];   // 16 KB
    __shared__ __hip_bfloat16 wsm[MA * MA];    // 8 KB
    __shared__ float smem[MA * F];             // 32 KB: u_f (64x128) or t1 tile (16x512)
    __shared__ float r_lds[MA][4];             // 1 KB
    __shared__ float mask_lds[MA];

    const float* hg = h + (size_t)n * MA * F;

    // ---- stage h -> bf16 LDS (coalesced float4) ----
    for (int idx = tid; idx < MA * F / 4; idx += 512) {
        float4 v4 = ((const float4*)hg)[idx];
        int b = idx * 4;
        h_lds[b + 0] = __float2bfloat16(v4.x);
        h_lds[b + 1] = __float2bfloat16(v4.y);
        h_lds[b + 2] = __float2bfloat16(v4.z);
        h_lds[b + 3] = __float2bfloat16(v4.w);
    }
    if (tid < MA) {
        mask_lds[tid] = (z[n * MA + tid] > -1) ? 1.0f : 0.0f;
        r_lds[tid][0] = rr[(n * MA + tid) * 3 + 0];
        r_lds[tid][1] = rr[(n * MA + tid) * 3 + 1];
        r_lds[tid][2] = rr[(n * MA + tid) * 3 + 2];
    }
    __syncthreads();

    // t1 accumulator: thread tid owns column j=tid of t1 (64 rows)
    float acc[MA];
    #pragma unroll
    for (int a = 0; a < MA; a++) acc[a] = 0.0f;

    // ---- GEMM1, h-part (k = 0..127): acc[a] += h[a][k] * W1[k][tid] ----
    {
        const float* w1c = W1 + tid;
        for (int k = 0; k < F; k += 4) {
            float wa = w1c[(k + 0) * HID];
            float wb = w1c[(k + 1) * HID];
            float wc = w1c[(k + 2) * HID];
            float wd = w1c[(k + 3) * HID];
            #pragma unroll
            for (int a = 0; a < MA; a++) {
                const __hip_bfloat162* hp = (const __hip_bfloat162*)&h_lds[a * F + k];
                __hip_bfloat162 p0 = hp[0];
                __hip_bfloat162 p1 = hp[1];
                acc[a] = fmaf(__bfloat162float(p0.x), wa, acc[a]);
                acc[a] = fmaf(__bfloat162float(p0.y), wb, acc[a]);
                acc[a] = fmaf(__bfloat162float(p1.x), wc, acc[a]);
                acc[a] = fmaf(__bfloat162float(p1.y), wd, acc[a]);
            }
        }
    }

    // ---- per-filter: w_f -> u_f -> GEMM1 u-part ----
    for (int f = 0; f < NF; f++) {
        float mu = dist[f];
        float sg = wid[f];
        // w_f[a][b] = mask_a*mask_b * exp(-((d-mu)^2)/sigma) * 5
        for (int idx = tid; idx < MA * MA; idx += 512) {
            int a = idx >> 6, b = idx & 63;
            float dx = r_lds[a][0] - r_lds[b][0];
            float dy = r_lds[a][1] - r_lds[b][1];
            float dz = r_lds[a][2] - r_lds[b][2];
            float d = sqrtf(dx * dx + dy * dy + dz * dz + 1e-12f);
            float t = d - mu;
            float wv = mask_lds[a] * mask_lds[b] * expf(-t * t / sg) * 5.0f;
            wsm[idx] = __float2bfloat16(wv);
        }
        __syncthreads();   // SYNC1: wsm ready; also guarantees prev-f GEMM reads of smem done
        // u_f[a][c] = sum_b w_f[a][b] * h[b][c]  (each thread: 8 a's x 2 c's)
        {
            int c2 = tid & 63;   // c = 2*c2
            int ag = tid >> 6;   // 0..7
            for (int i = 0; i < 8; i++) {
                int a = ag * 8 + i;
                float a0 = 0.f, a1 = 0.f;
                for (int b = 0; b < MA; b++) {
                    float wv = __bfloat162float(wsm[a * MA + b]);   // LDS broadcast
                    __hip_bfloat162 h2 = *(const __hip_bfloat162*)&h_lds[b * F + c2 * 2];
                    a0 = fmaf(wv, __bfloat162float(h2.x), a0);
                    a1 = fmaf(wv, __bfloat162float(h2.y), a1);
                }
                smem[a * F + c2 * 2]     = a0;
                smem[a * F + c2 * 2 + 1] = a1;
            }
        }
        __syncthreads();   // SYNC2: u_f ready
        // acc[a] += u_f[a][k] * W1[128 + f*128 + k][tid]
        {
            const float* w1c = W1 + (size_t)(F + f * F) * HID + tid;
            for (int k = 0; k < F; k += 4) {
                float wa = w1c[(k + 0) * HID];
                float wb = w1c[(k + 1) * HID];
                float wc = w1c[(k + 2) * HID];
                float wd = w1c[(k + 3) * HID];
                #pragma unroll
                for (int a = 0; a < MA; a++) {
                    float4 uv = *(const float4*)&smem[a * F + k];   // LDS broadcast b128
                    acc[a] = fmaf(uv.x, wa, acc[a]);
                    acc[a] = fmaf(uv.y, wb, acc[a]);
                    acc[a] = fmaf(uv.z, wc, acc[a]);
                    acc[a] = fmaf(uv.w, wd, acc[a]);
                }
            }
        }
    }

    // ---- bias + silu ----
    float bj = b1[tid];
    #pragma unroll
    for (int a = 0; a < MA; a++) {
        float x = acc[a] + bj;
        acc[a] = x / (1.0f + expf(-x));
    }

    // ---- GEMM2 in 4 tiles of 16 atoms (LDS transpose), fused epilogue ----
    #pragma unroll 4
    for (int tile = 0; tile < 4; tile++) {
        __syncthreads();   // prev readers of smem done
        #pragma unroll
        for (int i = 0; i < 16; i++) {
            smem[i * HID + tid] = acc[tile * 16 + i];
        }
        __syncthreads();
        int c4 = tid & 31;   // covers c = 4*c4 .. 4*c4+3
        int al = tid >> 5;   // 0..15
        int a = tile * 16 + al;
        float o0 = 0.f, o1 = 0.f, o2 = 0.f, o3 = 0.f;
        for (int j = 0; j < HID; j += 4) {
            float4 s4 = *(const float4*)&smem[al * HID + j];
            const float* w2r = &W2[(size_t)j * F + c4 * 4];
            float4 q0 = *(const float4*)(w2r);
            float4 q1 = *(const float4*)(w2r + F);
            float4 q2 = *(const float4*)(w2r + 2 * F);
            float4 q3 = *(const float4*)(w2r + 3 * F);
            o0 = fmaf(s4.x, q0.x, o0); o1 = fmaf(s4.x, q0.y, o1);
            o2 = fmaf(s4.x, q0.z, o2); o3 = fmaf(s4.x, q0.w, o3);
            o0 = fmaf(s4.y, q1.x, o0); o1 = fmaf(s4.y, q1.y, o1);
            o2 = fmaf(s4.y, q1.z, o2); o3 = fmaf(s4.y, q1.w, o3);
            o0 = fmaf(s4.z, q2.x, o0); o1 = fmaf(s4.z, q2.y, o1);
            o2 = fmaf(s4.z, q2.z, o2); o3 = fmaf(s4.z, q2.w, o3);
            o0 = fmaf(s4.w, q3.x, o0); o1 = fmaf(s4.w, q3.y, o1);
            o2 = fmaf(s4.w, q3.z, o2); o3 = fmaf(s4.w, q3.w, o3);
        }
        float m = mask_lds[a] * 0.1f;   // UPDATE_RATIO * DECAY
        float4 hv = *(const float4*)&hg[a * F + c4 * 4];
        float4 res;
        res.x = hv.x + (o0 + b2[c4 * 4 + 0]) * m;
        res.y = hv.y + (o1 + b2[c4 * 4 + 1]) * m;
        res.z = hv.z + (o2 + b2[c4 * 4 + 2]) * m;
        res.w = hv.w + (o3 + b2[c4 * 4 + 3]) * m;
        *(float4*)&out_h[(size_t)n * MA * F + a * F + c4 * 4] = res;
    }
}

extern "C" void kernel_launch(void* const* d_in, const int* in_sizes, int n_in,
                              void* d_out, int out_size, void* d_ws, size_t ws_size,
                              hipStream_t stream) {
    const int*   z    = (const int*)d_in[0];
    const float* r    = (const float*)d_in[1];
    const float* h    = (const float*)d_in[2];
    const float* dist = (const float*)d_in[3];
    const float* wid  = (const float*)d_in[4];
    const float* W1   = (const float*)d_in[5];
    const float* b1   = (const float*)d_in[6];
    const float* W2   = (const float*)d_in[7];
    const float* b2   = (const float*)d_in[8];
    float* out = (float*)d_out;

    int N = in_sizes[0] / MA;          // 512
    int nz = N * MA;                   // 32768
    int nr = N * MA * 3;               // 98304
    int npass = nz + nr;

    pass_kernel<<<(npass + 255) / 256, 256, 0, stream>>>(z, r, out, nz, nr);
    node_conv_kernel<<<N, 512, 0, stream>>>(z, r, h, dist, wid, W1, b1, W2, b2,
                                            out + nz + nr);
}

// Round 2
// 217.716 us; speedup vs baseline: 11.6911x; 11.6911x over previous
//
#include <hip/hip_runtime.h>

#define MA 64
#define F 128
#define NF 16
#define HID 512
#define LDU 136   // row stride (bf16 elems) for u / staged-h  (128 + 8 pad)
#define LDT 72    // row stride for hT and w                   (64 + 8 pad)
#define LDT1 520  // row stride for t1 half-buffer             (512 + 8 pad)

typedef float  float4v __attribute__((ext_vector_type(4)));
typedef short  short8  __attribute__((ext_vector_type(8)));

static __device__ __forceinline__ unsigned short f2bf(float x) {
    unsigned int u = __float_as_uint(x);
    unsigned int r = (u + 0x7fffu + ((u >> 16) & 1u)) >> 16;  // RNE
    return (unsigned short)r;
}

// ---- Phase 0: pack W1 as MFMA B-fragments, W2 as MFMA A-fragments (bf16) ----
// B-frag (16x16x32): lane l holds B[k0+(l>>4)*8+j][n0+(l&15)], j=0..7 contiguous.
// A-frag:            lane l holds A[m0+(l&15)][k0+(l>>4)*8+j].
__global__ void pack_weights(const float* __restrict__ W1, const float* __restrict__ W2,
                             unsigned short* __restrict__ w1p, unsigned short* __restrict__ w2p) {
    __shared__ unsigned short s[32 * 512];
    const int tid = threadIdx.x;
    const int blk = blockIdx.x;
    if (blk < 68) {                                   // W1: kt tile of 32 k-rows x 512 n
        const float* src = W1 + (size_t)blk * 32 * 512;
        for (int i = tid; i < 32 * 512 / 4; i += 256) {
            float4 v = ((const float4*)src)[i];
            s[4 * i + 0] = f2bf(v.x); s[4 * i + 1] = f2bf(v.y);
            s[4 * i + 2] = f2bf(v.z); s[4 * i + 3] = f2bf(v.w);
        }
        __syncthreads();
        for (int t = tid; t < 32 * 64; t += 256) {    // nt (32) x lane (64)
            int nt = t >> 6, l = t & 63;
            int kq = (l >> 4) * 8, nn = nt * 16 + (l & 15);
            short8 o;
            #pragma unroll
            for (int j = 0; j < 8; j++) o[j] = (short)s[(kq + j) * 512 + nn];
            *(short8*)(w1p + ((size_t)(blk * 32 + nt) * 64 + l) * 8) = o;
        }
    } else {                                          // W2: A-frags of W2^T (c x j)
        int kt = blk - 68;                            // 0..15 over j
        const float* src = W2 + (size_t)kt * 32 * 128;
        for (int i = tid; i < 32 * 128 / 4; i += 256) {
            float4 v = ((const float4*)src)[i];
            s[4 * i + 0] = f2bf(v.x); s[4 * i + 1] = f2bf(v.y);
            s[4 * i + 2] = f2bf(v.z); s[4 * i + 3] = f2bf(v.w);
        }
        __syncthreads();
        for (int t = tid; t < 8 * 64; t += 256) {     // mt (8) x lane
            int mt = t >> 6, l = t & 63;
            int kq = (l >> 4) * 8, cc = mt * 16 + (l & 15);
            short8 o;
            #pragma unroll
            for (int j = 0; j < 8; j++) o[j] = (short)s[(kq + j) * 128 + cc];
            *(short8*)(w2p + ((size_t)(kt * 8 + mt) * 64 + l) * 8) = o;
        }
    }
}

// ---- Main fused kernel: one block per molecule, 512 threads = 8 waves ----
__launch_bounds__(512)
__global__ void node_conv_mfma(const int* __restrict__ z, const float* __restrict__ rr,
        const float* __restrict__ h, const float* __restrict__ dist,
        const float* __restrict__ wid, const float* __restrict__ b1,
        const float* __restrict__ b2,
        const unsigned short* __restrict__ w1p, const unsigned short* __restrict__ w2p,
        float* __restrict__ out) {
    const int n = blockIdx.x;
    const int tid = threadIdx.x;
    const int lane = tid & 63;
    const int wave = tid >> 6;
    const int arow = lane & 15;          // MFMA frag row / D col
    const int kgrp = (lane >> 4) * 8;    // MFMA frag k-group

    // LDS union: [hT 128x72 | w 64x72 | u 64x136] bf16 = 45056 B; t1 32x520 overlays from 0
    __shared__ __attribute__((aligned(16))) unsigned short lds[22528];
    unsigned short* hT = lds;            // 9216 elems
    unsigned short* wL = lds + 9216;     // 4608 elems
    unsigned short* uL = lds + 13824;    // 8704 elems (h staged here for segment 0)
    unsigned short* t1 = lds;            // 16640 elems (overlay, live only in GEMM2)
    __shared__ float r_lds[MA][4];       // xyz + mask

    // ---- z / r passthrough + r/mask staging ----
    {
        int N = gridDim.x;
        if (tid < MA) out[(size_t)n * MA + tid] = (float)z[n * MA + tid];
        if (tid < 3 * MA) out[(size_t)N * MA + (size_t)n * 3 * MA + tid] = rr[(size_t)n * 3 * MA + tid];
        if (tid < MA) {
            r_lds[tid][0] = rr[(n * MA + tid) * 3 + 0];
            r_lds[tid][1] = rr[(n * MA + tid) * 3 + 1];
            r_lds[tid][2] = rr[(n * MA + tid) * 3 + 2];
            r_lds[tid][3] = (z[n * MA + tid] > -1) ? 1.0f : 0.0f;
        }
    }

    // ---- stage h -> uL (row-major, padded) and hT (transposed, padded) ----
    const float* hg = h + (size_t)n * MA * F;
    for (int i = tid; i < MA * F / 4; i += 512) {
        float4 v = ((const float4*)hg)[i];
        int a = i >> 5;
        int c = (i & 31) * 4;
        unsigned short e0 = f2bf(v.x), e1 = f2bf(v.y), e2 = f2bf(v.z), e3 = f2bf(v.w);
        uL[a * LDU + c + 0] = e0; uL[a * LDU + c + 1] = e1;
        uL[a * LDU + c + 2] = e2; uL[a * LDU + c + 3] = e3;
        hT[(c + 0) * LDT + a] = e0; hT[(c + 1) * LDT + a] = e1;
        hT[(c + 2) * LDT + a] = e2; hT[(c + 3) * LDT + a] = e3;
    }
    __syncthreads();

    // ---- per-thread pairwise distances (hoisted out of filter loop) ----
    const int wa = tid >> 3;             // atom a: 0..63
    const int wb0 = (tid & 7) * 8;       // atom b block: 8 entries
    float dpre[8], pm[8];
    {
        float ax = r_lds[wa][0], ay = r_lds[wa][1], az = r_lds[wa][2];
        float am5 = 5.0f * r_lds[wa][3];
        #pragma unroll
        for (int j = 0; j < 8; j++) {
            float dx = ax - r_lds[wb0 + j][0];
            float dy = ay - r_lds[wb0 + j][1];
            float dz = az - r_lds[wb0 + j][2];
            dpre[j] = sqrtf(dx * dx + dy * dy + dz * dz + 1e-12f);
            pm[j] = am5 * r_lds[wb0 + j][3];
        }
    }

    const float4v zf = {0.f, 0.f, 0.f, 0.f};
    float4v acc[4][4];                   // t1 slab: rows a=mt*16.., cols j=wave*64+nt*16..
    #pragma unroll
    for (int i = 0; i < 4; i++)
        #pragma unroll
        for (int j = 0; j < 4; j++) acc[i][j] = zf;

    // ---- main loop: 17 K-segments of 128 (seg 0 = h, segs 1..16 = u_f) ----
    for (int f = 0; f <= NF; f++) {
        // GEMM1 segment: A = uL (padded 136), B = packed W1 (global, L2-hot)
        for (int ks = 0; ks < 4; ks++) {
            short8 af[4];
            #pragma unroll
            for (int mt = 0; mt < 4; mt++)
                af[mt] = *(const short8*)&uL[(mt * 16 + arow) * LDU + ks * 32 + kgrp];
            const int kt = f * 4 + ks;
            short8 bfv[4];
            #pragma unroll
            for (int nt = 0; nt < 4; nt++)
                bfv[nt] = *(const short8*)(w1p + ((size_t)(kt * 32 + wave * 4 + nt) * 64 + lane) * 8);
            #pragma unroll
            for (int mt = 0; mt < 4; mt++)
                #pragma unroll
                for (int nt = 0; nt < 4; nt++)
                    acc[mt][nt] = __builtin_amdgcn_mfma_f32_16x16x32_bf16(af[mt], bfv[nt], acc[mt][nt], 0, 0, 0);
        }
        __syncthreads();                 // all uL / wL readers done

        if (f < NF) {
            // w_f (VALU; overlaps surrounding MFMA via wave co-scheduling)
            float mu = dist[f];
            float isg = 1.0f / wid[f];
            short8 wpk;
            #pragma unroll
            for (int j = 0; j < 8; j++) {
                float t = dpre[j] - mu;
                wpk[j] = (short)f2bf(pm[j] * __expf(-t * t * isg));
            }
            *(short8*)&wL[wa * LDT + wb0] = wpk;
            __syncthreads();             // w visible

            // u_f = w @ h : A = wL, B = hT; each wave: n-tile = wave (c slab of 16)
            float4v ud[4];
            #pragma unroll
            for (int mt = 0; mt < 4; mt++) ud[mt] = zf;
            #pragma unroll
            for (int ks2 = 0; ks2 < 2; ks2++) {
                short8 bh = *(const short8*)&hT[(wave * 16 + arow) * LDT + ks2 * 32 + kgrp];
                #pragma unroll
                for (int mt = 0; mt < 4; mt++) {
                    short8 awf = *(const short8*)&wL[(mt * 16 + arow) * LDT + ks2 * 32 + kgrp];
                    ud[mt] = __builtin_amdgcn_mfma_f32_16x16x32_bf16(awf, bh, ud[mt], 0, 0, 0);
                }
            }
            // write u (C-layout -> row-major padded): safe, all uL readers passed barrier A
            #pragma unroll
            for (int mt = 0; mt < 4; mt++) {
                int abase = mt * 16 + (lane >> 4) * 4;
                #pragma unroll
                for (int r = 0; r < 4; r++)
                    uL[(abase + r) * LDU + wave * 16 + arow] = f2bf(ud[mt][r]);
            }
            __syncthreads();             // u visible for next segment
        }
    }

    // ---- GEMM2: out = h + 0.1*mask*(silu(t1) @ W2 + b2), two 32-atom halves ----
    float b1v[4];
    #pragma unroll
    for (int nt = 0; nt < 4; nt++) b1v[nt] = b1[wave * 64 + nt * 16 + arow];
    float* outh = out + (size_t)gridDim.x * MA * 4 + (size_t)n * MA * F;

    for (int hh = 0; hh < 2; hh++) {
        if (hh == 1) __syncthreads();    // prior GEMM2 reads of t1 done
        #pragma unroll
        for (int mt = 0; mt < 2; mt++) { // m-tiles 2hh, 2hh+1
            int mtg = 2 * hh + mt;
            int rloc = mt * 16 + (lane >> 4) * 4;
            #pragma unroll
            for (int nt = 0; nt < 4; nt++) {
                #pragma unroll
                for (int r = 0; r < 4; r++) {
                    float x = acc[mtg][nt][r] + b1v[nt];
                    float s = x / (1.0f + __expf(-x));
                    t1[(rloc + r) * LDT1 + wave * 64 + nt * 16 + arow] = f2bf(s);
                }
            }
        }
        __syncthreads();                 // t1 half visible

        float4v g2[2] = {zf, zf};
        for (int ks = 0; ks < 16; ks++) {
            short8 aw2 = *(const short8*)(w2p + ((size_t)(ks * 8 + wave) * 64 + lane) * 8);
            #pragma unroll
            for (int n2 = 0; n2 < 2; n2++) {
                short8 bt = *(const short8*)&t1[(n2 * 16 + arow) * LDT1 + ks * 32 + kgrp];
                g2[n2] = __builtin_amdgcn_mfma_f32_16x16x32_bf16(aw2, bt, g2[n2], 0, 0, 0);
            }
        }
        // epilogue: D[m=c][n=a_local]; lane: a = hh*32+n2*16+arow, c = wave*16+(l>>4)*4+r
        #pragma unroll
        for (int n2 = 0; n2 < 2; n2++) {
            int a = hh * 32 + n2 * 16 + arow;
            int c0 = wave * 16 + (lane >> 4) * 4;
            float m = r_lds[a][3] * 0.1f;
            float4 hv = *(const float4*)(hg + a * F + c0);
            float4 b2v = *(const float4*)(b2 + c0);
            float4 res;
            res.x = hv.x + (g2[n2][0] + b2v.x) * m;
            res.y = hv.y + (g2[n2][1] + b2v.y) * m;
            res.z = hv.z + (g2[n2][2] + b2v.z) * m;
            res.w = hv.w + (g2[n2][3] + b2v.w) * m;
            *(float4*)(outh + a * F + c0) = res;
        }
    }
}

extern "C" void kernel_launch(void* const* d_in, const int* in_sizes, int n_in,
                              void* d_out, int out_size, void* d_ws, size_t ws_size,
                              hipStream_t stream) {
    const int*   z    = (const int*)d_in[0];
    const float* rr   = (const float*)d_in[1];
    const float* h    = (const float*)d_in[2];
    const float* dist = (const float*)d_in[3];
    const float* wid  = (const float*)d_in[4];
    const float* W1   = (const float*)d_in[5];
    const float* b1   = (const float*)d_in[6];
    const float* W2   = (const float*)d_in[7];
    const float* b2   = (const float*)d_in[8];
    float* out = (float*)d_out;

    int N = in_sizes[0] / MA;                          // 512 molecules

    unsigned short* w1p = (unsigned short*)d_ws;       // 68*32*64*8 bf16 = 2.23 MB
    unsigned short* w2p = w1p + (size_t)68 * 32 * 64 * 8;  // 16*8*64*8 bf16 = 128 KB

    pack_weights<<<84, 256, 0, stream>>>(W1, W2, w1p, w2p);
    node_conv_mfma<<<N, 512, 0, stream>>>(z, rr, h, dist, wid, b1, b2, w1p, w2p, out);
}